// Round 8
// baseline (398.739 us; speedup 1.0000x reference)
//
#include <hip/hip_runtime.h>

// GCNEncoder — round 18: WIDE gathers + scan fused into hist.
// - k_agg1: 8B/lane gather (lane=half*32+q reads uint2 of row ss[j+half]) —
//   2 rows per load instruction instead of 1 (was 4B/lane). Halves load
//   instructions, doubles bytes per outstanding miss request. Per-node
//   totals combined with one __shfl_xor(32) add. A/B test: if k_agg1 is
//   miss-slot-bound this is ~+30%; if L3-path-BW-bound it is null (then the
//   gather is at roofline).
// - k_agg2: same idea at 4 rows/load (quad scheme, was 2B/lane).
// - k_scan fused into k_hist via last-block pattern (threadfence + done
//   counter; last block's 256 threads run the 1024-entry scan). One fewer
//   serializing launch.
// Everything else identical to R17 (380.0us best).

#define SHIFT 8
#define BSZ   256          // nodes per bucket = 1<<SHIFT
#define CHUNK 4096         // edges per block in hist/scatter
#define EPT   (CHUNK/256)  // edges per thread = 16
#define NBMAX 1024         // supports N <= 262144

typedef short bf16x8 __attribute__((ext_vector_type(8)));
typedef float f32x4  __attribute__((ext_vector_type(4)));

__device__ __forceinline__ unsigned short f2bf(float f) {
    unsigned int u = __float_as_uint(f);
    unsigned int r = (u + 0x7FFFu + ((u >> 16) & 1u)) >> 16;   // RNE
    return (unsigned short)r;
}
__device__ __forceinline__ float bf2f(unsigned short h) {
    return __uint_as_float(((unsigned int)h) << 16);
}
// exact hi/lo split of a float pair, packed as bf16x2 (truncation split:
// x == bf2f(hi) + lo exactly; lo then truncated to bf16, residual ~2^-17|x|)
__device__ __forceinline__ void split2(float a, float b, unsigned int& hi, unsigned int& lo) {
    unsigned int ua = __float_as_uint(a), ub = __float_as_uint(b);
    unsigned int ha = ua & 0xFFFF0000u,  hb = ub & 0xFFFF0000u;
    hi = (ha >> 16) | hb;
    float la = a - __uint_as_float(ha);
    float lb = b - __uint_as_float(hb);
    lo = (__float_as_uint(la) >> 16) | (__float_as_uint(lb) & 0xFFFF0000u);
}
// dtype probe, computed per-block (reads 16 L2-hot ints): 1 => int64 input
__device__ __forceinline__ int detect64(const int* __restrict__ p) {
    int o = 0;
#pragma unroll
    for (int q = 0; q < 16; ++q) o |= p[2 * q + 1];
    return (o == 0) ? 1 : 0;
}

// ---------- prep: W1+W2 -> fragment bf16 hi/lo buffers + zero gcnt/spart ----
__global__ __launch_bounds__(256) void k_prep(const float* __restrict__ W1,
                                              const float* __restrict__ W2,
                                              uint4* __restrict__ Whi1,
                                              uint4* __restrict__ Wlo1,
                                              uint4* __restrict__ Whi2,
                                              uint4* __restrict__ Wlo2,
                                              int* __restrict__ gcnt,
                                              float* __restrict__ spart,
                                              int* __restrict__ done) {
    int gid = blockIdx.x * 256 + threadIdx.x;   // 16 blocks = 4096 threads
    if (gid < 1024) gcnt[gid] = 0;
    if (gid == 0) done[0] = 0;
    for (int u = gid; u < 16384; u += 4096) spart[u] = 0.f;
    const float* W; uint4 *H, *L; int slot;
    if (gid < 2048)      { W = W1; H = Whi1; L = Wlo1; slot = gid; }
    else if (gid < 3072) { W = W2; H = Whi2; L = Wlo2; slot = gid - 2048; }
    else return;
    int lane = slot & 63, kt = (slot >> 6) & 3, nt = slot >> 8;
    int o = nt * 16 + (lane & 15);
    int k0 = kt * 32 + (lane >> 4) * 8;
    const float* p = W + (size_t)o * 128 + k0;
    unsigned int h[4], l[4];
#pragma unroll
    for (int pr = 0; pr < 4; ++pr) split2(p[2 * pr], p[2 * pr + 1], h[pr], l[pr]);
    H[slot] = make_uint4(h[0], h[1], h[2], h[3]);
    L[slot] = make_uint4(l[0], l[1], l[2], l[3]);
}

// ---------- pass 1: bucket histogram + fused last-block scan ----------
__global__ __launch_bounds__(256) void k_hist(const void* __restrict__ eiv,
                                              int* __restrict__ gcnt,
                                              int* __restrict__ gbase,
                                              int* __restrict__ gcur,
                                              int* __restrict__ done,
                                              int E, int N, int NB) {
    __shared__ int h[NBMAX];
    __shared__ int ssum[256];
    __shared__ int lastflag;
    int t = threadIdx.x;
    for (int u = t; u < NB; u += 256) h[u] = 0;
    __syncthreads();
    int base = blockIdx.x * CHUNK;
    int f = detect64((const int*)eiv);
    const long long* e64 = (const long long*)eiv;
    const int*       e32 = (const int*)eiv;
#pragma unroll
    for (int r = 0; r < EPT; ++r) {
        int e = base + r * 256 + t;
        if (e < E) {
            int s, d;
            if (f) { s = (int)e64[e]; d = (int)e64[E + e]; }
            else   { s = e32[e];      d = e32[E + e]; }
            if ((unsigned)s < (unsigned)N && (unsigned)d < (unsigned)N)
                atomicAdd(&h[d >> SHIFT], 1);
        }
    }
    __syncthreads();
    for (int u = t; u < NB; u += 256) {
        int c = h[u];
        if (c) atomicAdd(&gcnt[u], c);
    }
    // ---- last-block scan (replaces k_scan) ----
    __threadfence();
    if (t == 0) lastflag = (atomicAdd(done, 1) == (int)gridDim.x - 1) ? 1 : 0;
    __syncthreads();
    if (!lastflag) return;
    __threadfence();   // acquire: other blocks' gcnt atomics
    int v0 = gcnt[4 * t], v1 = gcnt[4 * t + 1], v2 = gcnt[4 * t + 2], v3 = gcnt[4 * t + 3];
    int tsum = v0 + v1 + v2 + v3;
    ssum[t] = tsum;
    __syncthreads();
    for (int o = 1; o < 256; o <<= 1) {
        int x = ssum[t];
        int y = (t >= o) ? ssum[t - o] : 0;
        __syncthreads();
        ssum[t] = x + y;
        __syncthreads();
    }
    int ex = ssum[t] - tsum;
    int e0 = ex, e1 = ex + v0, e2 = e1 + v1, e3 = e2 + v2;
    gbase[4 * t] = e0;     gcur[4 * t] = e0;
    gbase[4 * t + 1] = e1; gcur[4 * t + 1] = e1;
    gbase[4 * t + 2] = e2; gcur[4 * t + 2] = e2;
    gbase[4 * t + 3] = e3; gcur[4 * t + 3] = e3;
    if (t == 255) gbase[NB] = ssum[255];
}

// ---------- pass 3: scatter edges into bucket regions, clustered ----------
__global__ __launch_bounds__(256) void k_scatter(const void* __restrict__ eiv,
                                                 int* __restrict__ gcur,
                                                 unsigned int* __restrict__ ebuf,
                                                 int E, int N, int NB) {
    __shared__ int lcnt[NBMAX];
    __shared__ int lbase[NBMAX];
    int t = threadIdx.x;
    for (int u = t; u < NB; u += 256) lcnt[u] = 0;
    __syncthreads();
    int base = blockIdx.x * CHUNK;
    int f = detect64((const int*)eiv);
    const long long* e64 = (const long long*)eiv;
    const int*       e32 = (const int*)eiv;
    unsigned int ent[EPT];
    int bk[EPT];
    int off[EPT];
#pragma unroll
    for (int r = 0; r < EPT; ++r) {
        int e = base + r * 256 + t;
        bk[r] = -1;
        if (e < E) {
            int s, d;
            if (f) { s = (int)e64[e]; d = (int)e64[E + e]; }
            else   { s = e32[e];      d = e32[E + e]; }
            if ((unsigned)s < (unsigned)N && (unsigned)d < (unsigned)N) {
                int b = d >> SHIFT;
                bk[r]  = b;
                off[r] = atomicAdd(&lcnt[b], 1);
                ent[r] = ((unsigned int)(d & (BSZ - 1)) << 24) | (unsigned int)s;
            }
        }
    }
    __syncthreads();
    for (int u = t; u < NB; u += 256) {
        int c = lcnt[u];
        lbase[u] = c ? atomicAdd(&gcur[u], c) : 0;
    }
    __syncthreads();
#pragma unroll
    for (int r = 0; r < EPT; ++r)
        if (bk[r] >= 0) ebuf[(size_t)lbase[bk[r]] + off[r]] = ent[r];
}

// ---------- pass 4: per-bucket CSR finalize (counts, dis, rowptr, elist) ----
__global__ __launch_bounds__(256) void k_fine(const unsigned int* __restrict__ ebuf,
                                              const int* __restrict__ gbase,
                                              int* __restrict__ cnt,
                                              float* __restrict__ dis,
                                              int* __restrict__ rowptr,
                                              int* __restrict__ elist, int N) {
    __shared__ int lc[BSZ];
    __shared__ int ls[BSZ];
    int t = threadIdx.x;
    int b = blockIdx.x;
    int start = gbase[b], end = gbase[b + 1];
    int m = end - start;
    lc[t] = 0;
    __syncthreads();
    for (int j = t; j < m; j += 256)
        atomicAdd(&lc[ebuf[start + j] >> 24], 1);
    __syncthreads();
    int v = lc[t];
    ls[t] = v;
    __syncthreads();
    for (int off = 1; off < BSZ; off <<= 1) {
        int x = ls[t];
        int y = (t >= off) ? ls[t - off] : 0;
        __syncthreads();
        ls[t] = x + y;
        __syncthreads();
    }
    int ex = ls[t] - v;
    int i = (b << SHIFT) + t;
    if (i < N) {
        cnt[i]    = v;
        dis[i]    = rsqrtf((float)v + 1.0f);
        rowptr[i] = start + ex;
    }
    lc[t] = ex;        // per-node cursor (bucket-relative)
    __syncthreads();
    for (int j = t; j < m; j += 256) {
        unsigned int e = ebuf[start + j];
        int p = atomicAdd(&lc[e >> 24], 1);
        elist[start + p] = (int)(e & 0xFFFFFFu);
    }
}

// ---------- GEMM1 (MFMA): h1s[n][o] (bf16) = dis[n] * (x[n]·W1[o]) ----------
__global__ __launch_bounds__(256) void k_gemm1(const float* __restrict__ x,
                                               const uint4* __restrict__ Whi,
                                               const uint4* __restrict__ Wlo,
                                               const float* __restrict__ dis,
                                               unsigned short* __restrict__ h1b, int N) {
    __shared__ uint4 Ahi[1024];   // [ (c*4+kt)*64 + lane ]
    __shared__ uint4 Alo[1024];
    int t = threadIdx.x;
    int n0 = blockIdx.x * 64;
    // ---- phase 1: x -> hi/lo fragments in LDS ----
    for (int s = t; s < 1024; s += 256) {
        int lane = s & 63, kt = (s >> 6) & 3, c = s >> 8;
        int row = n0 + c * 16 + (lane & 15);
        int rr = min(row, N - 1);
        int k0 = kt * 32 + (lane >> 4) * 8;
        const float4* p = (const float4*)(x + (size_t)rr * 128 + k0);
        float4 u0 = p[0], u1 = p[1];
        unsigned int h0, h1, h2, h3, l0, l1, l2, l3;
        split2(u0.x, u0.y, h0, l0);
        split2(u0.z, u0.w, h1, l1);
        split2(u1.x, u1.y, h2, l2);
        split2(u1.z, u1.w, h3, l3);
        Ahi[s] = make_uint4(h0, h1, h2, h3);
        Alo[s] = make_uint4(l0, l1, l2, l3);
    }
    __syncthreads();
    // ---- phase 2: MFMA ----
    int w = t >> 6, lane = t & 63;
    bf16x8 ah[4], al[4];
#pragma unroll
    for (int kt = 0; kt < 4; ++kt) {
        ah[kt] = ((const bf16x8*)Ahi)[(w * 4 + kt) * 64 + lane];
        al[kt] = ((const bf16x8*)Alo)[(w * 4 + kt) * 64 + lane];
    }
    f32x4 acc[8];
#pragma unroll
    for (int nt = 0; nt < 8; ++nt) {
        acc[nt] = (f32x4)(0.f);
#pragma unroll
        for (int kt = 0; kt < 4; ++kt) {
            bf16x8 bh = ((const bf16x8*)Whi)[(nt * 4 + kt) * 64 + lane];
            bf16x8 bl = ((const bf16x8*)Wlo)[(nt * 4 + kt) * 64 + lane];
            acc[nt] = __builtin_amdgcn_mfma_f32_16x16x32_bf16(ah[kt], bh, acc[nt], 0, 0, 0);
            acc[nt] = __builtin_amdgcn_mfma_f32_16x16x32_bf16(ah[kt], bl, acc[nt], 0, 0, 0);
            acc[nt] = __builtin_amdgcn_mfma_f32_16x16x32_bf16(al[kt], bh, acc[nt], 0, 0, 0);
        }
    }
    // ---- epilogue: scale by dis, pack bf16, store ----
    int r0 = n0 + w * 16 + (lane >> 4) * 4;
    float dv[4];
#pragma unroll
    for (int r = 0; r < 4; ++r) {
        int row = r0 + r;
        dv[r] = (row < N) ? dis[row] : 0.f;
    }
#pragma unroll
    for (int nt = 0; nt < 8; ++nt) {
        int col = nt * 16 + (lane & 15);
#pragma unroll
        for (int r = 0; r < 4; ++r) {
            int row = r0 + r;
            if (row < N) h1b[(size_t)row * 128 + col] = f2bf(dv[r] * acc[nt][r]);
        }
    }
}

// ---------- layer-1 gather (WIDE: uint2/lane, 2 rows per load) + BN-stats ----
// lane = half*32+q: loads feats 4q..4q+3 (uint2) of edge pair-member `half`.
// Halves combined once per node via __shfl_xor(32). 16 nodes/block.
__global__ __launch_bounds__(256) void k_agg1(const unsigned int* __restrict__ h1b,
                                              const float* __restrict__ dis,
                                              const int* __restrict__ rowptr,
                                              const int* __restrict__ cnt,
                                              const int* __restrict__ elist,
                                              float* __restrict__ agg1,
                                              float* __restrict__ spart, int N) {
    int t = threadIdx.x;
    int lane = t & 63;
    int q = lane & 31;        // feature uint2 index (feats 4q..4q+3)
    int half = lane >> 5;     // which pair-member this lane gathers
    int i0 = blockIdx.x * 16 + (t >> 6) * 4;
    float s0 = 0.f, s1 = 0.f, s2 = 0.f, s3 = 0.f;   // BN sums (half0)
    float q0 = 0.f, q1 = 0.f, q2 = 0.f, q3 = 0.f;   // BN sumsqs
#pragma unroll
    for (int k = 0; k < 4; ++k) {
        int i = i0 + k;
        bool act = (i < N);
        float f0 = 0.f, f1 = 0.f, f2 = 0.f, f3 = 0.f;
        int base = 0, c = 0;
        if (act) { base = rowptr[i]; c = cnt[i]; }
        int j = 0;
        for (; j + 16 <= c; j += 16) {
            int ss[16];
#pragma unroll
            for (int r = 0; r < 16; ++r) ss[r] = elist[base + j + r];
            uint2 vv[8];
#pragma unroll
            for (int r = 0; r < 8; ++r)
                vv[r] = *(const uint2*)(h1b + (size_t)ss[2 * r + half] * 64 + 2 * q);
#pragma unroll
            for (int r = 0; r < 8; ++r) {
                f0 += bf2f((unsigned short)(vv[r].x & 0xFFFF));
                f1 += bf2f((unsigned short)(vv[r].x >> 16));
                f2 += bf2f((unsigned short)(vv[r].y & 0xFFFF));
                f3 += bf2f((unsigned short)(vv[r].y >> 16));
            }
        }
        if (j + 8 <= c) {
            int ss[8];
#pragma unroll
            for (int r = 0; r < 8; ++r) ss[r] = elist[base + j + r];
            uint2 vv[4];
#pragma unroll
            for (int r = 0; r < 4; ++r)
                vv[r] = *(const uint2*)(h1b + (size_t)ss[2 * r + half] * 64 + 2 * q);
#pragma unroll
            for (int r = 0; r < 4; ++r) {
                f0 += bf2f((unsigned short)(vv[r].x & 0xFFFF));
                f1 += bf2f((unsigned short)(vv[r].x >> 16));
                f2 += bf2f((unsigned short)(vv[r].y & 0xFFFF));
                f3 += bf2f((unsigned short)(vv[r].y >> 16));
            }
            j += 8;
        }
        if (j + 2 <= c) {   // pairs
            int n2 = (c - j) >> 1;
            for (int p = 0; p < n2; ++p) {
                int s = elist[base + j + 2 * p + half];
                uint2 v = *(const uint2*)(h1b + (size_t)s * 64 + 2 * q);
                f0 += bf2f((unsigned short)(v.x & 0xFFFF));
                f1 += bf2f((unsigned short)(v.x >> 16));
                f2 += bf2f((unsigned short)(v.y & 0xFFFF));
                f3 += bf2f((unsigned short)(v.y >> 16));
            }
            j += 2 * n2;
        }
        if (j < c && half == 0) {   // single tail edge
            int s = elist[base + j];
            uint2 v = *(const uint2*)(h1b + (size_t)s * 64 + 2 * q);
            f0 += bf2f((unsigned short)(v.x & 0xFFFF));
            f1 += bf2f((unsigned short)(v.x >> 16));
            f2 += bf2f((unsigned short)(v.y & 0xFFFF));
            f3 += bf2f((unsigned short)(v.y >> 16));
        }
        // combine halves (both end with the full sum)
        f0 += __shfl_xor(f0, 32, 64);
        f1 += __shfl_xor(f1, 32, 64);
        f2 += __shfl_xor(f2, 32, 64);
        f3 += __shfl_xor(f3, 32, 64);
        if (act) {
            float di = dis[i];
            uint2 sv = *(const uint2*)(h1b + (size_t)i * 64 + 2 * q);
            float r0 = di * (f0 + bf2f((unsigned short)(sv.x & 0xFFFF)));
            float r1 = di * (f1 + bf2f((unsigned short)(sv.x >> 16)));
            float r2 = di * (f2 + bf2f((unsigned short)(sv.y & 0xFFFF)));
            float r3 = di * (f3 + bf2f((unsigned short)(sv.y >> 16)));
            if (half == 0) {
                *(float4*)(agg1 + (size_t)i * 128 + 4 * q) = make_float4(r0, r1, r2, r3);
                s0 += r0; s1 += r1; s2 += r2; s3 += r3;
                q0 += r0 * r0; q1 += r1 * r1; q2 += r2 * r2; q3 += r3 * r3;
            }
        }
    }
    // ---- BN partial reduce: half0 lanes hold feats 4q..4q+3 ----
    __shared__ float4 reds[128], redq[128];
    int w = t >> 6;
    if (half == 0) {
        reds[w * 32 + q] = make_float4(s0, s1, s2, s3);
        redq[w * 32 + q] = make_float4(q0, q1, q2, q3);
    }
    __syncthreads();
    if (t < 32) {
        float4 a = reds[t], b = reds[t + 32], c = reds[t + 64], d = reds[t + 96];
        float4 e = redq[t], f = redq[t + 32], g = redq[t + 64], h = redq[t + 96];
        float* sp = spart + ((size_t)(blockIdx.x & 63) << 8);
        atomicAdd(&sp[4 * t + 0],       a.x + b.x + c.x + d.x);
        atomicAdd(&sp[4 * t + 1],       a.y + b.y + c.y + d.y);
        atomicAdd(&sp[4 * t + 2],       a.z + b.z + c.z + d.z);
        atomicAdd(&sp[4 * t + 3],       a.w + b.w + c.w + d.w);
        atomicAdd(&sp[128 + 4 * t + 0], e.x + f.x + g.x + h.x);
        atomicAdd(&sp[128 + 4 * t + 1], e.y + f.y + g.y + h.y);
        atomicAdd(&sp[128 + 4 * t + 2], e.z + f.z + g.z + h.z);
        atomicAdd(&sp[128 + 4 * t + 3], e.w + f.w + g.w + h.w);
    }
}

// ---------- GEMM2 (MFMA) + fused BN finalize ----------
__global__ __launch_bounds__(256) void k_gemm2(const float* __restrict__ agg1,
                                               const uint4* __restrict__ Whi,
                                               const uint4* __restrict__ Wlo,
                                               const float* __restrict__ spart,
                                               const float* __restrict__ gamma,
                                               const float* __restrict__ beta,
                                               const float* __restrict__ dis,
                                               unsigned short* __restrict__ h2b, int N) {
    __shared__ uint4 Ahi[1024];   // [ (c*4+kt)*64 + lane ]
    __shared__ uint4 Alo[1024];
    __shared__ float sred[256];
    __shared__ float bnsc[128], bnsh[128];
    int t = threadIdx.x;
    int n0 = blockIdx.x * 64;
    // ---- phase 0: BN finalize (redundant per block; spart is L2-hot) ----
    {
        float s = 0.f;
        for (int sl = 0; sl < 64; ++sl) s += spart[sl * 256 + t];
        sred[t] = s;
        __syncthreads();
        if (t < 128) {
            float invN = 1.0f / (float)N;
            float mean = sred[t] * invN;
            float var = sred[128 + t] * invN - mean * mean;
            var = fmaxf(var, 0.f);
            float inv = rsqrtf(var + 1e-5f);
            float sc = gamma[t] * inv;
            bnsc[t] = sc;
            bnsh[t] = beta[t] - mean * sc;
        }
        __syncthreads();
    }
    // ---- phase 1: relu(bn(agg1)) -> hi/lo fragments in LDS ----
    for (int s = t; s < 1024; s += 256) {
        int lane = s & 63, kt = (s >> 6) & 3, c = s >> 8;
        int row = n0 + c * 16 + (lane & 15);
        int rr = min(row, N - 1);
        int k0 = kt * 32 + (lane >> 4) * 8;
        const float4* p = (const float4*)(agg1 + (size_t)rr * 128 + k0);
        float4 a0 = p[0], a1 = p[1];
        float v0 = fmaxf(a0.x * bnsc[k0 + 0] + bnsh[k0 + 0], 0.f);
        float v1 = fmaxf(a0.y * bnsc[k0 + 1] + bnsh[k0 + 1], 0.f);
        float v2 = fmaxf(a0.z * bnsc[k0 + 2] + bnsh[k0 + 2], 0.f);
        float v3 = fmaxf(a0.w * bnsc[k0 + 3] + bnsh[k0 + 3], 0.f);
        float v4 = fmaxf(a1.x * bnsc[k0 + 4] + bnsh[k0 + 4], 0.f);
        float v5 = fmaxf(a1.y * bnsc[k0 + 5] + bnsh[k0 + 5], 0.f);
        float v6 = fmaxf(a1.z * bnsc[k0 + 6] + bnsh[k0 + 6], 0.f);
        float v7 = fmaxf(a1.w * bnsc[k0 + 7] + bnsh[k0 + 7], 0.f);
        unsigned int h0, h1, h2, h3, l0, l1, l2, l3;
        split2(v0, v1, h0, l0);
        split2(v2, v3, h1, l1);
        split2(v4, v5, h2, l2);
        split2(v6, v7, h3, l3);
        Ahi[s] = make_uint4(h0, h1, h2, h3);
        Alo[s] = make_uint4(l0, l1, l2, l3);
    }
    __syncthreads();
    // ---- phase 2: MFMA (4 nt x 4 kt x 3) ----
    int w = t >> 6, lane = t & 63;
    bf16x8 ah[4], al[4];
#pragma unroll
    for (int kt = 0; kt < 4; ++kt) {
        ah[kt] = ((const bf16x8*)Ahi)[(w * 4 + kt) * 64 + lane];
        al[kt] = ((const bf16x8*)Alo)[(w * 4 + kt) * 64 + lane];
    }
    f32x4 acc[4];
#pragma unroll
    for (int nt = 0; nt < 4; ++nt) {
        acc[nt] = (f32x4)(0.f);
#pragma unroll
        for (int kt = 0; kt < 4; ++kt) {
            bf16x8 bh = ((const bf16x8*)Whi)[(nt * 4 + kt) * 64 + lane];
            bf16x8 bl = ((const bf16x8*)Wlo)[(nt * 4 + kt) * 64 + lane];
            acc[nt] = __builtin_amdgcn_mfma_f32_16x16x32_bf16(ah[kt], bh, acc[nt], 0, 0, 0);
            acc[nt] = __builtin_amdgcn_mfma_f32_16x16x32_bf16(ah[kt], bl, acc[nt], 0, 0, 0);
            acc[nt] = __builtin_amdgcn_mfma_f32_16x16x32_bf16(al[kt], bh, acc[nt], 0, 0, 0);
        }
    }
    // ---- epilogue: scale by dis, pack bf16, store (64 cols) ----
    int r0 = n0 + w * 16 + (lane >> 4) * 4;
    float dv[4];
#pragma unroll
    for (int r = 0; r < 4; ++r) {
        int row = r0 + r;
        dv[r] = (row < N) ? dis[row] : 0.f;
    }
#pragma unroll
    for (int nt = 0; nt < 4; ++nt) {
        int col = nt * 16 + (lane & 15);
#pragma unroll
        for (int r = 0; r < 4; ++r) {
            int row = r0 + r;
            if (row < N) h2b[(size_t)row * 64 + col] = f2bf(dv[r] * acc[nt][r]);
        }
    }
}

// ---------- layer-2 gather (WIDE: uint2/lane, 4 rows per load) ----------
// lane = quad*16+q: loads feats 4q..4q+3 (uint2) of edge quad-member.
// Quads combined via __shfl_xor(16)+__shfl_xor(32).
__global__ __launch_bounds__(256) void k_agg2(const unsigned int* __restrict__ h2b,
                                              const float* __restrict__ dis,
                                              const int* __restrict__ rowptr,
                                              const int* __restrict__ cnt,
                                              const int* __restrict__ elist,
                                              const float* __restrict__ b2,
                                              float* __restrict__ out, int N) {
    int lane = threadIdx.x & 63;
    int q = lane & 15;        // feature uint2 index (feats 4q..4q+3 of 64)
    int quad = lane >> 4;     // which quad-member this lane gathers
    int i = blockIdx.x * 4 + (threadIdx.x >> 6);
    if (i >= N) return;
    float f0 = 0.f, f1 = 0.f, f2 = 0.f, f3 = 0.f;
    int base = rowptr[i], c = cnt[i];
    int j = 0;
    for (; j + 16 <= c; j += 16) {
        int ss[16];
#pragma unroll
        for (int r = 0; r < 16; ++r) ss[r] = elist[base + j + r];
        uint2 vv[4];
#pragma unroll
        for (int r = 0; r < 4; ++r)
            vv[r] = *(const uint2*)(h2b + (size_t)ss[4 * r + quad] * 32 + 2 * q);
#pragma unroll
        for (int r = 0; r < 4; ++r) {
            f0 += bf2f((unsigned short)(vv[r].x & 0xFFFF));
            f1 += bf2f((unsigned short)(vv[r].x >> 16));
            f2 += bf2f((unsigned short)(vv[r].y & 0xFFFF));
            f3 += bf2f((unsigned short)(vv[r].y >> 16));
        }
    }
    if (j + 4 <= c) {   // quads
        int n4 = (c - j) >> 2;
        for (int p = 0; p < n4; ++p) {
            int s = elist[base + j + 4 * p + quad];
            uint2 v = *(const uint2*)(h2b + (size_t)s * 32 + 2 * q);
            f0 += bf2f((unsigned short)(v.x & 0xFFFF));
            f1 += bf2f((unsigned short)(v.x >> 16));
            f2 += bf2f((unsigned short)(v.y & 0xFFFF));
            f3 += bf2f((unsigned short)(v.y >> 16));
        }
        j += 4 * n4;
    }
    for (; j < c; ++j) {   // singles: quad 0 lanes only
        if (quad == 0) {
            int s = elist[base + j];
            uint2 v = *(const uint2*)(h2b + (size_t)s * 32 + 2 * q);
            f0 += bf2f((unsigned short)(v.x & 0xFFFF));
            f1 += bf2f((unsigned short)(v.x >> 16));
            f2 += bf2f((unsigned short)(v.y & 0xFFFF));
            f3 += bf2f((unsigned short)(v.y >> 16));
        }
    }
    // combine quads
    f0 += __shfl_xor(f0, 16, 64); f0 += __shfl_xor(f0, 32, 64);
    f1 += __shfl_xor(f1, 16, 64); f1 += __shfl_xor(f1, 32, 64);
    f2 += __shfl_xor(f2, 16, 64); f2 += __shfl_xor(f2, 32, 64);
    f3 += __shfl_xor(f3, 16, 64); f3 += __shfl_xor(f3, 32, 64);
    float di = dis[i];
    uint2 sv = *(const uint2*)(h2b + (size_t)i * 32 + 2 * q);
    if (quad == 0) {
        float4 bb = ((const float4*)b2)[q];
        float o0 = di * (f0 + bf2f((unsigned short)(sv.x & 0xFFFF))) + bb.x;
        float o1 = di * (f1 + bf2f((unsigned short)(sv.x >> 16)))    + bb.y;
        float o2 = di * (f2 + bf2f((unsigned short)(sv.y & 0xFFFF))) + bb.z;
        float o3 = di * (f3 + bf2f((unsigned short)(sv.y >> 16)))    + bb.w;
        *(float4*)(out + (size_t)i * 64 + 4 * q) = make_float4(o0, o1, o2, o3);
    }
}

extern "C" void kernel_launch(void* const* d_in, const int* in_sizes, int n_in,
                              void* d_out, int out_size, void* d_ws, size_t ws_size,
                              hipStream_t stream) {
    const float* x     = (const float*)d_in[0];
    const void*  ei    = d_in[1];            // int64 or int32, probed per-block
    const float* W1    = (const float*)d_in[2];
    // d_in[3] = b1: cancels exactly through BatchNorm -> skipped
    const float* gamma = (const float*)d_in[4];
    const float* beta  = (const float*)d_in[5];
    const float* W2    = (const float*)d_in[6];
    const float* b2    = (const float*)d_in[7];
    float* out = (float*)d_out;

    int N = in_sizes[0] / 128;
    int E = in_sizes[1] / 2;
    int NB = (N + BSZ - 1) >> SHIFT;         // 391 buckets for N=100000 (<= NBMAX)

    // ---- workspace layout (~85 MB; all regions 16B-aligned) ----
    size_t Na = ((size_t)N + 3) & ~(size_t)3;
    size_t Ea = ((size_t)E + 3) & ~(size_t)3;
    int*   cnt    = (int*)d_ws;                          // Na
    int*   rowptr = cnt + Na;                            // Na
    int*   gcnt   = rowptr + Na;                         // 1024
    int*   gbase  = gcnt + 1024;                         // 1028 (NB+1 used)
    int*   gcur   = gbase + 1028;                        // 1024
    int*   done   = gcur + 1024;                         // 1 (in old stats region)
    float* stats  = (float*)(gcur + 1024);               // 512 (done shares [0])
    float* spart  = stats + 512;                         // 64*256 = 16K floats
    float* dis    = spart + 65536;                       // Na
    int*   elist  = (int*)(dis + Na);                    // Ea
    unsigned int* h1b = (unsigned int*)(elist + Ea);     // Na*64 uints (bf16x2)
    float* agg1   = (float*)(h1b + Na * 64);             // Na*128 f32
    unsigned int* ebuf = (unsigned int*)agg1;            // overlay: dead before k_agg1
    uint4* Whi1   = (uint4*)(agg1 + Na * 128);           // 2048 uint4 = 32 KB
    uint4* Wlo1   = Whi1 + 2048;                         // 32 KB
    uint4* Whi2   = Wlo1 + 2048;                         // 1024 uint4 = 16 KB
    uint4* Wlo2   = Whi2 + 1024;                         // 16 KB
    unsigned int* h2b = h1b;                             // overlay: h1 dead after agg1

    int gC    = (E + CHUNK - 1) / CHUNK;     // 391 chunks
    int gG1   = (N + 63) / 64;               // MFMA gemms: 64 rows/block
    int gAgg1 = (N + 15) / 16;               // 16 nodes/block
    int gAgg2 = (N + 3) / 4;

    k_prep<<<16, 256, 0, stream>>>(W1, W2, Whi1, Wlo1, Whi2, Wlo2, gcnt, spart, done);
    k_hist<<<gC, 256, 0, stream>>>(ei, gcnt, gbase, gcur, done, E, N, NB);
    k_scatter<<<gC, 256, 0, stream>>>(ei, gcur, ebuf, E, N, NB);
    k_fine<<<NB, 256, 0, stream>>>(ebuf, gbase, cnt, dis, rowptr, elist, N);
    k_gemm1<<<gG1, 256, 0, stream>>>(x, Whi1, Wlo1, dis, (unsigned short*)h1b, N);
    k_agg1<<<gAgg1, 256, 0, stream>>>(h1b, dis, rowptr, cnt, elist, agg1, spart, N);
    k_gemm2<<<gG1, 256, 0, stream>>>(agg1, Whi2, Wlo2, spart, gamma, beta, dis, (unsigned short*)h2b, N);
    k_agg2<<<gAgg2, 256, 0, stream>>>((const unsigned int*)h2b, dis, rowptr, cnt, elist, b2, out, N);
}